// Round 1
// baseline (1678.350 us; speedup 1.0000x reference)
//
#include <hip/hip_runtime.h>
#include <math.h>

#define B_    8
#define SEQ_  4096
#define CIN_  7
#define DM_   512
#define NL_   4
#define PL_   16
#define NP_   256
#define NS_   16
#define DC_   4
#define DI_   1024
#define DTR_  32
#define CD_   64
#define PRED_ 96
#define TOK_  (B_*NP_)   // 2048
#define EPS_  1e-5f

__device__ __forceinline__ float silu_f(float x){ return x / (1.f + __expf(-x)); }
__device__ __forceinline__ float softplus_f(float x){ return x > 20.f ? x : log1pf(__expf(x)); }

// ---------------- LN over CIN=7 (input) ----------------
__global__ void ln7_kernel(const float* __restrict__ x, const float* __restrict__ g,
                           const float* __restrict__ b, float* __restrict__ o){
  int i = blockIdx.x*256 + threadIdx.x; // over B*SEQ
  if (i >= B_*SEQ_) return;
  float v[CIN_]; float m = 0.f;
  #pragma unroll
  for (int c=0;c<CIN_;c++){ v[c]=x[i*CIN_+c]; m+=v[c]; }
  m *= (1.f/CIN_);
  float var = 0.f;
  #pragma unroll
  for (int c=0;c<CIN_;c++){ float d=v[c]-m; var+=d*d; }
  var *= (1.f/CIN_);
  float r = rsqrtf(var + EPS_);
  #pragma unroll
  for (int c=0;c<CIN_;c++) o[i*CIN_+c] = (v[c]-m)*r*g[c]+b[c];
}

// ---------------- patch embed: h[b,n,d] = sum_{c,p} xln[b,n*16+p,c]*peW[d,c,p] + peb[d]
__global__ __launch_bounds__(256) void embed_kernel(const float* __restrict__ xln,
    const float* __restrict__ peW, const float* __restrict__ peb, float* __restrict__ h){
  __shared__ float sp[112];
  int bn = blockIdx.x;            // b*256 + n
  int b = bn >> 8, n = bn & 255;
  int tid = threadIdx.x;
  if (tid < 112){
    int c = tid >> 4, p = tid & 15;
    sp[tid] = xln[((size_t)b*SEQ_ + n*PL_ + p)*CIN_ + c];
  }
  __syncthreads();
  #pragma unroll
  for (int half = 0; half < 2; half++){
    int d = tid + half*256;
    float acc = peb[d];
    const float* w = peW + d*112;
    #pragma unroll 14
    for (int k = 0; k < 112; k++) acc += sp[k]*w[k];
    h[(size_t)bn*DM_ + d] = acc;
  }
}

// ---------------- LN over DM=512 ----------------
__global__ __launch_bounds__(256) void ln512_kernel(const float* __restrict__ in,
    const float* __restrict__ g, const float* __restrict__ b, float* __restrict__ out){
  __shared__ float red[256];
  int t = blockIdx.x, tid = threadIdx.x;
  float v0 = in[(size_t)t*DM_+tid], v1 = in[(size_t)t*DM_+tid+256];
  red[tid] = v0+v1; __syncthreads();
  for (int s=128;s>0;s>>=1){ if (tid<s) red[tid]+=red[tid+s]; __syncthreads(); }
  float m = red[0] * (1.f/DM_); __syncthreads();
  float d0 = v0-m, d1 = v1-m;
  red[tid] = d0*d0+d1*d1; __syncthreads();
  for (int s=128;s>0;s>>=1){ if (tid<s) red[tid]+=red[tid+s]; __syncthreads(); }
  float r = rsqrtf(red[0]*(1.f/DM_) + EPS_);
  out[(size_t)t*DM_+tid]     = d0*r*g[tid]+b[tid];
  out[(size_t)t*DM_+tid+256] = d1*r*g[tid+256]+b[tid+256];
}

// ---------------- fp32 NT GEMM: C[M,N] = A[M,K] * B[N,K]^T ; 64x64 tile ----------------
template<bool ACC>
__global__ __launch_bounds__(256) void gemm_nt(const float* __restrict__ A, const float* __restrict__ Bm,
    float* __restrict__ C, int K, int lda, int ldb, int ldc){
  __shared__ float As[16][65];
  __shared__ float Bs[16][65];
  int bm = blockIdx.y*64, bn = blockIdx.x*64;
  int tid = threadIdx.x;
  int lk = tid & 15, lr = tid >> 4;   // loader coords
  int tx = tid & 15, ty = tid >> 4;   // compute coords
  float acc[4][4] = {};
  for (int k0 = 0; k0 < K; k0 += 16){
    #pragma unroll
    for (int i = 0; i < 4; i++){
      As[lk][lr+i*16] = A[(size_t)(bm+lr+i*16)*lda + k0 + lk];
      Bs[lk][lr+i*16] = Bm[(size_t)(bn+lr+i*16)*ldb + k0 + lk];
    }
    __syncthreads();
    #pragma unroll
    for (int k = 0; k < 16; k++){
      float av[4], bv[4];
      #pragma unroll
      for (int i = 0; i < 4; i++){ av[i]=As[k][ty*4+i]; bv[i]=Bs[k][tx*4+i]; }
      #pragma unroll
      for (int i = 0; i < 4; i++)
        #pragma unroll
        for (int j = 0; j < 4; j++) acc[i][j] += av[i]*bv[j];
    }
    __syncthreads();
  }
  #pragma unroll
  for (int i = 0; i < 4; i++){
    int m = bm + ty*4 + i;
    #pragma unroll
    for (int j = 0; j < 4; j++){
      int nn = bn + tx*4 + j;
      if (ACC) C[(size_t)m*ldc+nn] += acc[i][j];
      else     C[(size_t)m*ldc+nn]  = acc[i][j];
    }
  }
}

// ---------------- causal depthwise conv (DC=4) + bias + silu ----------------
__global__ void conv_silu_kernel(const float* __restrict__ xz, const float* __restrict__ cW,
                                 const float* __restrict__ cb, float* __restrict__ xc){
  int idx = blockIdx.x*256 + threadIdx.x;   // TOK*DI
  if (idx >= TOK_*DI_) return;
  int c = idx & (DI_-1); int t = idx >> 10; int l = t & (NP_-1);
  float acc = cb[c];
  const float* w = cW + c*DC_;
  #pragma unroll
  for (int k = 0; k < DC_; k++){
    int ls = l - (DC_-1) + k;
    if (ls >= 0) acc += xz[(size_t)(t - l + ls)*(2*DI_) + c] * w[k];
  }
  xc[idx] = silu_f(acc);
}

// ---------------- dbl[t,e] = sum_k xc[t,k]*W_x[e,k]  (e<64), uses transposed wxT[k][e]
__global__ __launch_bounds__(256) void dbl_kernel(const float* __restrict__ xc,
    const float* __restrict__ wxT, float* __restrict__ dbl){
  int wave = threadIdx.x >> 6; int lane = threadIdx.x & 63;
  int t = blockIdx.x*4 + wave;
  const float* xr = xc + (size_t)t*DI_;
  float acc = 0.f;
  for (int k = 0; k < DI_; k += 4){
    float4 xv = *(const float4*)(xr + k);
    acc += xv.x*wxT[(k+0)*64+lane];
    acc += xv.y*wxT[(k+1)*64+lane];
    acc += xv.z*wxT[(k+2)*64+lane];
    acc += xv.w*wxT[(k+3)*64+lane];
  }
  dbl[(size_t)t*64 + lane] = acc;
}

// ---------------- delta[t,d] = softplus(sum_r dt[t,r]*W_dt[d,r] + b_dt[d]) ----------------
__global__ __launch_bounds__(256) void delta_kernel(const float* __restrict__ dbl,
    const float* __restrict__ wdtT, const float* __restrict__ bdt, float* __restrict__ delta){
  __shared__ float sdt[DTR_];
  int t = blockIdx.y; int d = blockIdx.x*256 + threadIdx.x;
  if (threadIdx.x < DTR_) sdt[threadIdx.x] = dbl[(size_t)t*64 + threadIdx.x];
  __syncthreads();
  float acc = bdt[d];
  #pragma unroll
  for (int r = 0; r < DTR_; r++) acc += sdt[r]*wdtT[r*DI_ + d];
  delta[(size_t)t*DI_ + d] = softplus_f(acc);
}

// ---------------- selective scan: n in lanes (16 per d), y via shfl reduce ----------------
__global__ __launch_bounds__(256) void scan_kernel(const float* __restrict__ delta,
    const float* __restrict__ xc, const float* __restrict__ dbl,
    const float* __restrict__ Alog, float* __restrict__ y){
  int tid = threadIdx.x;
  int n = tid & 15, dg = tid >> 4;
  int d = blockIdx.x*16 + dg;
  int b = blockIdx.y;
  float A = -__expf(Alog[d*NS_ + n]);
  float h = 0.f;
  int base = b*NP_;
  for (int t = 0; t < NP_; t++){
    int row = base + t;
    float de = delta[(size_t)row*DI_ + d];
    float xv = xc[(size_t)row*DI_ + d];
    float Bv = dbl[(size_t)row*64 + 32 + n];
    float Cv = dbl[(size_t)row*64 + 48 + n];
    float a = __expf(de*A);
    h = a*h + de*Bv*xv;
    float p = h*Cv;
    p += __shfl_xor(p, 1);
    p += __shfl_xor(p, 2);
    p += __shfl_xor(p, 4);
    p += __shfl_xor(p, 8);
    if (n == 0) y[(size_t)row*DI_ + d] = p;
  }
}

// ---------------- y = (y + xc*Dv) * silu(z) ----------------
__global__ void ymix_kernel(float* __restrict__ y, const float* __restrict__ xc,
                            const float* __restrict__ xz, const float* __restrict__ Dv){
  int idx = blockIdx.x*256 + threadIdx.x;
  if (idx >= TOK_*DI_) return;
  int c = idx & (DI_-1), t = idx >> 10;
  float z = xz[(size_t)t*(2*DI_) + DI_ + c];
  y[idx] = (y[idx] + xc[idx]*Dv[c]) * silu_f(z);
}

// ---------------- head GEMM1 partials: per (n, kc) block, 8 m-accumulators ----------------
__global__ __launch_bounds__(256) void head1_kernel(const float* __restrict__ u,
    const float* __restrict__ hW1, float* __restrict__ partial){
  const int KTOT = DM_*NP_;        // 131072
  const int KLEN = KTOT/16;        // 8192
  int nidx = blockIdx.x;           // 0..127
  int kc   = blockIdx.y;           // 0..15
  int tid  = threadIdx.x;
  float acc[8] = {};
  const float* w = hW1 + (size_t)nidx*KTOT;
  for (int k = kc*KLEN + tid; k < (kc+1)*KLEN; k += 256){
    float wv = w[k];
    #pragma unroll
    for (int m = 0; m < 8; m++) acc[m] += u[(size_t)m*KTOT + k]*wv;
  }
  __shared__ float red[256];
  #pragma unroll
  for (int m = 0; m < 8; m++){
    red[tid] = acc[m]; __syncthreads();
    for (int s=128;s>0;s>>=1){ if (tid<s) red[tid]+=red[tid+s]; __syncthreads(); }
    if (tid == 0) partial[((size_t)kc*128 + nidx)*8 + m] = red[0];
    __syncthreads();
  }
}

__global__ void head_combine_kernel(const float* __restrict__ partial,
    const float* __restrict__ hb1, float* __restrict__ t1){
  int idx = blockIdx.x*256 + threadIdx.x;  // n*8+m, 1024 total
  if (idx >= 128*8) return;
  int n = idx >> 3, m = idx & 7;
  float s = hb1[n];
  #pragma unroll
  for (int kc = 0; kc < 16; kc++) s += partial[((size_t)kc*128 + n)*8 + m];
  float ge = 0.5f*s*(1.f + erff(s*0.70710678118f));  // exact gelu
  t1[m*128 + n] = ge;
}

__global__ void head2_kernel(const float* __restrict__ t1, const float* __restrict__ hW2,
                             const float* __restrict__ hb2, float* __restrict__ out){
  int idx = blockIdx.x*128 + threadIdx.x;  // 8*96
  if (idx >= B_*PRED_) return;
  int m = idx / PRED_, q = idx % PRED_;
  float s = hb2[q];
  #pragma unroll 16
  for (int k = 0; k < 2*CD_; k++) s += t1[m*128 + k]*hW2[q*128 + k];
  out[idx] = s;
}

// ---------------- weight transposes (once per launch) ----------------
__global__ void prep_kernel(const float* __restrict__ W_dt, const float* __restrict__ W_x,
                            float* __restrict__ wdtT, float* __restrict__ wxT){
  int idx = blockIdx.x*256 + threadIdx.x;
  if (idx < NL_*DTR_*DI_){
    int l = idx / (DTR_*DI_); int rem = idx % (DTR_*DI_);
    int r = rem / DI_; int d = rem % DI_;
    wdtT[idx] = W_dt[((size_t)l*DI_ + d)*DTR_ + r];
  }
  if (idx < NL_*DI_*64){
    int l = idx / (DI_*64); int rem = idx % (DI_*64);
    int k = rem / 64; int e = rem % 64;
    wxT[idx] = W_x[((size_t)l*64 + e)*DI_ + k];
  }
}

extern "C" void kernel_launch(void* const* d_in, const int* in_sizes, int n_in,
                              void* d_out, int out_size, void* d_ws, size_t ws_size,
                              hipStream_t stream) {
  const float* x      = (const float*)d_in[0];
  const float* in_g   = (const float*)d_in[1];
  const float* in_b   = (const float*)d_in[2];
  const float* pe_W   = (const float*)d_in[3];
  const float* pe_b   = (const float*)d_in[4];
  const float* ln_g   = (const float*)d_in[5];
  const float* ln_b   = (const float*)d_in[6];
  const float* W_in   = (const float*)d_in[7];
  const float* conv_W = (const float*)d_in[8];
  const float* conv_b = (const float*)d_in[9];
  const float* W_x    = (const float*)d_in[10];
  const float* W_dt   = (const float*)d_in[11];
  const float* b_dt   = (const float*)d_in[12];
  const float* A_log  = (const float*)d_in[13];
  const float* Dskip  = (const float*)d_in[14];
  const float* W_out  = (const float*)d_in[15];
  const float* fn_g   = (const float*)d_in[16];
  const float* fn_b   = (const float*)d_in[17];
  const float* hW1    = (const float*)d_in[18];
  const float* hb1    = (const float*)d_in[19];
  const float* hW2    = (const float*)d_in[20];
  const float* hb2    = (const float*)d_in[21];

  float* ws    = (float*)d_ws;
  float* h     = ws;                    // 1,048,576
  float* un    = h     + 1048576;       // 1,048,576
  float* xz    = un    + 1048576;       // 4,194,304
  float* xc    = xz    + 4194304;       // 2,097,152
  float* dblb  = xc    + 2097152;       //   131,072
  float* delta = dblb  + 131072;        // 2,097,152
  float* y     = delta + 2097152;       // 2,097,152
  float* wdtT  = y     + 2097152;       //   131,072
  float* wxT   = wdtT  + 131072;        //   262,144  (total 13,107,200 floats = 50 MB)
  float* xln     = y;                   // prologue-only, overlays y
  float* partial = xz;                  // epilogue-only, overlays xz
  float* t1      = xz + 16384;

  prep_kernel<<<1024, 256, 0, stream>>>(W_dt, W_x, wdtT, wxT);
  ln7_kernel<<<(B_*SEQ_+255)/256, 256, 0, stream>>>(x, in_g, in_b, xln);
  embed_kernel<<<TOK_, 256, 0, stream>>>(xln, pe_W, pe_b, h);

  for (int l = 0; l < NL_; l++){
    ln512_kernel<<<TOK_, 256, 0, stream>>>(h, ln_g + l*DM_, ln_b + l*DM_, un);
    gemm_nt<false><<<dim3(2*DI_/64, TOK_/64), 256, 0, stream>>>(
        un, W_in + (size_t)l*2*DI_*DM_, xz, DM_, DM_, DM_, 2*DI_);
    conv_silu_kernel<<<(TOK_*DI_)/256, 256, 0, stream>>>(
        xz, conv_W + (size_t)l*DI_*DC_, conv_b + (size_t)l*DI_, xc);
    dbl_kernel<<<TOK_/4, 256, 0, stream>>>(xc, wxT + (size_t)l*DI_*64, dblb);
    delta_kernel<<<dim3(DI_/256, TOK_), 256, 0, stream>>>(
        dblb, wdtT + (size_t)l*DTR_*DI_, b_dt + (size_t)l*DI_, delta);
    scan_kernel<<<dim3(DI_/16, B_), 256, 0, stream>>>(
        delta, xc, dblb, A_log + (size_t)l*DI_*NS_, y);
    ymix_kernel<<<(TOK_*DI_)/256, 256, 0, stream>>>(y, xc, xz, Dskip + (size_t)l*DI_);
    gemm_nt<true><<<dim3(DM_/64, TOK_/64), 256, 0, stream>>>(
        y, W_out + (size_t)l*DM_*DI_, h, DI_, DI_, DI_, DM_);
  }

  ln512_kernel<<<TOK_, 256, 0, stream>>>(h, fn_g, fn_b, un);
  head1_kernel<<<dim3(128, 16), 256, 0, stream>>>(un, hW1, partial);
  head_combine_kernel<<<4, 256, 0, stream>>>(partial, hb1, t1);
  head2_kernel<<<6, 128, 0, stream>>>(t1, hW2, hb2, (float*)d_out);
}

// Round 2
// 948.858 us; speedup vs baseline: 1.7688x; 1.7688x over previous
//
#include <hip/hip_runtime.h>
#include <hip/hip_bf16.h>
#include <math.h>

#define B_    8
#define SEQ_  4096
#define CIN_  7
#define DM_   512
#define NL_   4
#define PL_   16
#define NP_   256
#define NS_   16
#define DC_   4
#define DI_   1024
#define DTR_  32
#define CD_   64
#define PRED_ 96
#define TOK_  (B_*NP_)   // 2048
#define EPS_  1e-5f

typedef unsigned short u16;
typedef __attribute__((ext_vector_type(8))) short short8;
typedef __attribute__((ext_vector_type(4))) float floatx4;

__device__ __forceinline__ float silu_f(float x){ return x / (1.f + __expf(-x)); }
__device__ __forceinline__ float softplus_f(float x){ return x > 20.f ? x : log1pf(__expf(x)); }
__device__ __forceinline__ u16 f2bf(float f){
  union { __hip_bfloat16 h; u16 u; } cv; cv.h = __float2bfloat16(f); return cv.u;
}

// ---------------- LN over CIN=7 (input) ----------------
__global__ void ln7_kernel(const float* __restrict__ x, const float* __restrict__ g,
                           const float* __restrict__ b, float* __restrict__ o){
  int i = blockIdx.x*256 + threadIdx.x; // over B*SEQ
  if (i >= B_*SEQ_) return;
  float v[CIN_]; float m = 0.f;
  #pragma unroll
  for (int c=0;c<CIN_;c++){ v[c]=x[i*CIN_+c]; m+=v[c]; }
  m *= (1.f/CIN_);
  float var = 0.f;
  #pragma unroll
  for (int c=0;c<CIN_;c++){ float d=v[c]-m; var+=d*d; }
  var *= (1.f/CIN_);
  float r = rsqrtf(var + EPS_);
  #pragma unroll
  for (int c=0;c<CIN_;c++) o[i*CIN_+c] = (v[c]-m)*r*g[c]+b[c];
}

// ---------------- patch embed ----------------
__global__ __launch_bounds__(256) void embed_kernel(const float* __restrict__ xln,
    const float* __restrict__ peW, const float* __restrict__ peb, float* __restrict__ h){
  __shared__ float sp[112];
  int bn = blockIdx.x;            // b*256 + n
  int b = bn >> 8, n = bn & 255;
  int tid = threadIdx.x;
  if (tid < 112){
    int c = tid >> 4, p = tid & 15;
    sp[tid] = xln[((size_t)b*SEQ_ + n*PL_ + p)*CIN_ + c];
  }
  __syncthreads();
  #pragma unroll
  for (int half = 0; half < 2; half++){
    int d = tid + half*256;
    float acc = peb[d];
    const float* w = peW + d*112;
    #pragma unroll 14
    for (int k = 0; k < 112; k++) acc += sp[k]*w[k];
    h[(size_t)bn*DM_ + d] = acc;
  }
}

// ---------------- LN over DM=512 (fp32 out + bf16 out) ----------------
__global__ __launch_bounds__(256) void ln512_kernel(const float* __restrict__ in,
    const float* __restrict__ g, const float* __restrict__ b,
    float* __restrict__ out, u16* __restrict__ outb){
  __shared__ float red[256];
  int t = blockIdx.x, tid = threadIdx.x;
  float v0 = in[(size_t)t*DM_+tid], v1 = in[(size_t)t*DM_+tid+256];
  red[tid] = v0+v1; __syncthreads();
  for (int s=128;s>0;s>>=1){ if (tid<s) red[tid]+=red[tid+s]; __syncthreads(); }
  float m = red[0] * (1.f/DM_); __syncthreads();
  float d0 = v0-m, d1 = v1-m;
  red[tid] = d0*d0+d1*d1; __syncthreads();
  for (int s=128;s>0;s>>=1){ if (tid<s) red[tid]+=red[tid+s]; __syncthreads(); }
  float r = rsqrtf(red[0]*(1.f/DM_) + EPS_);
  float o0 = d0*r*g[tid]+b[tid];
  float o1 = d1*r*g[tid+256]+b[tid+256];
  out[(size_t)t*DM_+tid]     = o0;
  out[(size_t)t*DM_+tid+256] = o1;
  outb[(size_t)t*DM_+tid]     = f2bf(o0);
  outb[(size_t)t*DM_+tid+256] = f2bf(o1);
}

// ---------------- bf16 MFMA NT GEMM: C[M,N](f32) = A[M,K]*B[N,K]^T ----------------
// A,B bf16 row-major. Block 256 thr = 4 waves (2x2), wave tile (BM/2)x(BN/2) of 16x16x32 mfma.
template<int BM, int BN, bool ACC>
__global__ __launch_bounds__(256) void gemm_bf16(const u16* __restrict__ A,
    const u16* __restrict__ Bw, float* __restrict__ C, int K, int lda, int ldb, int ldc){
  constexpr int MI = BM/32, NI = BN/32;
  __shared__ __align__(16) u16 As[BM*40];
  __shared__ __align__(16) u16 Bs[BN*40];
  int tid = threadIdx.x;
  int wave = tid>>6, lane = tid&63;
  int wm = wave>>1, wn = wave&1;
  int quad = lane>>4, l16 = lane&15;
  int bm = blockIdx.y*BM, bn = blockIdx.x*BN;
  int lrow = tid>>2, lseg = tid&3;
  floatx4 acc[MI][NI] = {};
  for (int k0 = 0; k0 < K; k0 += 32){
    #pragma unroll
    for (int r = 0; r < BM/64; r++){
      int row = lrow + r*64;
      *(int4*)&As[row*40 + lseg*8] = *(const int4*)&A[(size_t)(bm+row)*lda + k0 + lseg*8];
    }
    #pragma unroll
    for (int r = 0; r < BN/64; r++){
      int row = lrow + r*64;
      *(int4*)&Bs[row*40 + lseg*8] = *(const int4*)&Bw[(size_t)(bn+row)*ldb + k0 + lseg*8];
    }
    __syncthreads();
    short8 af[MI], bfr[NI];
    #pragma unroll
    for (int i = 0; i < MI; i++) af[i]  = *(short8*)&As[(wm*(BM/2)+i*16+l16)*40 + quad*8];
    #pragma unroll
    for (int j = 0; j < NI; j++) bfr[j] = *(short8*)&Bs[(wn*(BN/2)+j*16+l16)*40 + quad*8];
    #pragma unroll
    for (int i = 0; i < MI; i++)
      #pragma unroll
      for (int j = 0; j < NI; j++)
        acc[i][j] = __builtin_amdgcn_mfma_f32_16x16x32_bf16(af[i], bfr[j], acc[i][j], 0, 0, 0);
    __syncthreads();
  }
  #pragma unroll
  for (int i = 0; i < MI; i++){
    #pragma unroll
    for (int j = 0; j < NI; j++){
      #pragma unroll
      for (int r = 0; r < 4; r++){
        int m  = bm + wm*(BM/2) + i*16 + quad*4 + r;
        int nn = bn + wn*(BN/2) + j*16 + l16;
        if (ACC) C[(size_t)m*ldc+nn] += acc[i][j][r];
        else     C[(size_t)m*ldc+nn]  = acc[i][j][r];
      }
    }
  }
}

// ---------------- causal depthwise conv (DC=4) + bias + silu ----------------
__global__ void conv_silu_kernel(const float* __restrict__ xz, const float* __restrict__ cW,
                                 const float* __restrict__ cb, float* __restrict__ xc){
  int idx = blockIdx.x*256 + threadIdx.x;   // TOK*DI
  if (idx >= TOK_*DI_) return;
  int c = idx & (DI_-1); int t = idx >> 10; int l = t & (NP_-1);
  float acc = cb[c];
  const float* w = cW + c*DC_;
  #pragma unroll
  for (int k = 0; k < DC_; k++){
    int ls = l - (DC_-1) + k;
    if (ls >= 0) acc += xz[(size_t)(t - l + ls)*(2*DI_) + c] * w[k];
  }
  xc[idx] = silu_f(acc);
}

// ---------------- dbl[t,e] = sum_k xc[t,k]*W_x[e,k] ----------------
__global__ __launch_bounds__(256) void dbl_kernel(const float* __restrict__ xc,
    const float* __restrict__ wxT, float* __restrict__ dbl){
  int wave = threadIdx.x >> 6; int lane = threadIdx.x & 63;
  int t = blockIdx.x*4 + wave;
  const float* xr = xc + (size_t)t*DI_;
  float acc = 0.f;
  for (int k = 0; k < DI_; k += 4){
    float4 xv = *(const float4*)(xr + k);
    acc += xv.x*wxT[(k+0)*64+lane];
    acc += xv.y*wxT[(k+1)*64+lane];
    acc += xv.z*wxT[(k+2)*64+lane];
    acc += xv.w*wxT[(k+3)*64+lane];
  }
  dbl[(size_t)t*64 + lane] = acc;
}

// ---------------- delta = softplus(dt @ W_dt^T + b_dt) ----------------
__global__ __launch_bounds__(256) void delta_kernel(const float* __restrict__ dbl,
    const float* __restrict__ wdtT, const float* __restrict__ bdt, float* __restrict__ delta){
  __shared__ float sdt[DTR_];
  int t = blockIdx.y; int d = blockIdx.x*256 + threadIdx.x;
  if (threadIdx.x < DTR_) sdt[threadIdx.x] = dbl[(size_t)t*64 + threadIdx.x];
  __syncthreads();
  float acc = bdt[d];
  #pragma unroll
  for (int r = 0; r < DTR_; r++) acc += sdt[r]*wdtT[r*DI_ + d];
  delta[(size_t)t*DI_ + d] = softplus_f(acc);
}

// ---------------- selective scan: double-buffered prefetch, short serial chain ----------------
#define TC_ 8
#define LOAD_CHUNK(de_,xv_,Bv_,Cv_,t0_) do { \
  _Pragma("unroll") \
  for (int j = 0; j < TC_; j++){ \
    int row = base + (t0_) + j; \
    de_[j] = delta[(size_t)row*DI_ + d]; \
    xv_[j] = xc[(size_t)row*DI_ + d]; \
    Bv_[j] = dbl[(size_t)row*64 + 32 + n]; \
    Cv_[j] = dbl[(size_t)row*64 + 48 + n]; \
  } } while(0)
#define COMP_CHUNK(de_,xv_,Bv_,Cv_,t0_) do { \
  float a_[TC_], db_[TC_]; \
  _Pragma("unroll") \
  for (int j = 0; j < TC_; j++){ a_[j] = __expf(de_[j]*A); db_[j] = de_[j]*Bv_[j]*xv_[j]; } \
  _Pragma("unroll") \
  for (int j = 0; j < TC_; j++){ \
    h = a_[j]*h + db_[j]; \
    float p = h*Cv_[j]; \
    p += __shfl_xor(p,1); p += __shfl_xor(p,2); p += __shfl_xor(p,4); p += __shfl_xor(p,8); \
    if (n == 0) y[(size_t)(base+(t0_)+j)*DI_ + d] = p; \
  } } while(0)

__global__ __launch_bounds__(256) void scan_kernel(const float* __restrict__ delta,
    const float* __restrict__ xc, const float* __restrict__ dbl,
    const float* __restrict__ Alog, float* __restrict__ y){
  int tid = threadIdx.x;
  int n = tid & 15, dg = tid >> 4;
  int d = blockIdx.x*16 + dg;
  int b = blockIdx.y;
  float A = -__expf(Alog[d*NS_ + n]);
  float h = 0.f;
  int base = b*NP_;
  float de0[TC_], xv0[TC_], Bv0[TC_], Cv0[TC_];
  float de1[TC_], xv1[TC_], Bv1[TC_], Cv1[TC_];
  LOAD_CHUNK(de0, xv0, Bv0, Cv0, 0);
  for (int t0 = 0; t0 < NP_; t0 += 2*TC_){
    LOAD_CHUNK(de1, xv1, Bv1, Cv1, t0 + TC_);
    COMP_CHUNK(de0, xv0, Bv0, Cv0, t0);
    if (t0 + 2*TC_ < NP_) LOAD_CHUNK(de0, xv0, Bv0, Cv0, t0 + 2*TC_);
    COMP_CHUNK(de1, xv1, Bv1, Cv1, t0 + TC_);
  }
}

// ---------------- y = (y + xc*Dv) * silu(z) -> bf16 ----------------
__global__ void ymix_kernel(const float* __restrict__ y, const float* __restrict__ xc,
                            const float* __restrict__ xz, const float* __restrict__ Dv,
                            u16* __restrict__ yb){
  int idx = blockIdx.x*256 + threadIdx.x;
  if (idx >= TOK_*DI_) return;
  int c = idx & (DI_-1), t = idx >> 10;
  float z = xz[(size_t)t*(2*DI_) + DI_ + c];
  yb[idx] = f2bf((y[idx] + xc[idx]*Dv[c]) * silu_f(z));
}

// ---------------- head GEMM1 partials ----------------
__global__ __launch_bounds__(256) void head1_kernel(const float* __restrict__ u,
    const float* __restrict__ hW1, float* __restrict__ partial){
  const int KTOT = DM_*NP_;        // 131072
  const int KLEN = KTOT/16;        // 8192
  int nidx = blockIdx.x;           // 0..127
  int kc   = blockIdx.y;           // 0..15
  int tid  = threadIdx.x;
  float acc[8] = {};
  const float* w = hW1 + (size_t)nidx*KTOT;
  for (int k = kc*KLEN + tid; k < (kc+1)*KLEN; k += 256){
    float wv = w[k];
    #pragma unroll
    for (int m = 0; m < 8; m++) acc[m] += u[(size_t)m*KTOT + k]*wv;
  }
  __shared__ float red[256];
  #pragma unroll
  for (int m = 0; m < 8; m++){
    red[tid] = acc[m]; __syncthreads();
    for (int s=128;s>0;s>>=1){ if (tid<s) red[tid]+=red[tid+s]; __syncthreads(); }
    if (tid == 0) partial[((size_t)kc*128 + nidx)*8 + m] = red[0];
    __syncthreads();
  }
}

__global__ void head_combine_kernel(const float* __restrict__ partial,
    const float* __restrict__ hb1, float* __restrict__ t1){
  int idx = blockIdx.x*256 + threadIdx.x;  // n*8+m, 1024 total
  if (idx >= 128*8) return;
  int n = idx >> 3, m = idx & 7;
  float s = hb1[n];
  #pragma unroll
  for (int kc = 0; kc < 16; kc++) s += partial[((size_t)kc*128 + n)*8 + m];
  float ge = 0.5f*s*(1.f + erff(s*0.70710678118f));
  t1[m*128 + n] = ge;
}

__global__ void head2_kernel(const float* __restrict__ t1, const float* __restrict__ hW2,
                             const float* __restrict__ hb2, float* __restrict__ out){
  int idx = blockIdx.x*128 + threadIdx.x;  // 8*96
  if (idx >= B_*PRED_) return;
  int m = idx / PRED_, q = idx % PRED_;
  float s = hb2[q];
  #pragma unroll 16
  for (int k = 0; k < 2*CD_; k++) s += t1[m*128 + k]*hW2[q*128 + k];
  out[idx] = s;
}

// ---------------- prep: transposes + bf16 weight conversions ----------------
__global__ void prep_kernel(const float* __restrict__ W_dt, const float* __restrict__ W_x,
                            const float* __restrict__ W_in, const float* __restrict__ W_out,
                            float* __restrict__ wdtT, float* __restrict__ wxT,
                            u16* __restrict__ WinB, u16* __restrict__ WoutB){
  int idx = blockIdx.x*256 + threadIdx.x;
  if (idx < NL_*DTR_*DI_){
    int l = idx / (DTR_*DI_); int rem = idx % (DTR_*DI_);
    int r = rem / DI_; int d = rem % DI_;
    wdtT[idx] = W_dt[((size_t)l*DI_ + d)*DTR_ + r];
  }
  if (idx < NL_*DI_*64){
    int l = idx / (DI_*64); int rem = idx % (DI_*64);
    int k = rem / 64; int e = rem % 64;
    wxT[idx] = W_x[((size_t)l*64 + e)*DI_ + k];
  }
  if (idx < NL_*2*DI_*DM_) WinB[idx]  = f2bf(W_in[idx]);
  if (idx < NL_*DM_*DI_)   WoutB[idx] = f2bf(W_out[idx]);
}

extern "C" void kernel_launch(void* const* d_in, const int* in_sizes, int n_in,
                              void* d_out, int out_size, void* d_ws, size_t ws_size,
                              hipStream_t stream) {
  const float* x      = (const float*)d_in[0];
  const float* in_g   = (const float*)d_in[1];
  const float* in_b   = (const float*)d_in[2];
  const float* pe_W   = (const float*)d_in[3];
  const float* pe_b   = (const float*)d_in[4];
  const float* ln_g   = (const float*)d_in[5];
  const float* ln_b   = (const float*)d_in[6];
  const float* W_in   = (const float*)d_in[7];
  const float* conv_W = (const float*)d_in[8];
  const float* conv_b = (const float*)d_in[9];
  const float* W_x    = (const float*)d_in[10];
  const float* W_dt   = (const float*)d_in[11];
  const float* b_dt   = (const float*)d_in[12];
  const float* A_log  = (const float*)d_in[13];
  const float* Dskip  = (const float*)d_in[14];
  const float* W_out  = (const float*)d_in[15];
  const float* fn_g   = (const float*)d_in[16];
  const float* fn_b   = (const float*)d_in[17];
  const float* hW1    = (const float*)d_in[18];
  const float* hb1    = (const float*)d_in[19];
  const float* hW2    = (const float*)d_in[20];
  const float* hb2    = (const float*)d_in[21];

  float* ws    = (float*)d_ws;
  float* h     = ws;                    // 1,048,576 f
  float* un    = h     + 1048576;       // 1,048,576 f
  float* xz    = un    + 1048576;       // 4,194,304 f
  float* xc    = xz    + 4194304;       // 2,097,152 f
  float* dblb  = xc    + 2097152;       //   131,072 f
  float* delta = dblb  + 131072;        // 2,097,152 f
  float* y     = delta + 2097152;       // 2,097,152 f
  float* wdtT  = y     + 2097152;       //   131,072 f
  float* wxT   = wdtT  + 131072;        //   262,144 f
  float* bf_rgn= wxT   + 262144;
  u16*   unb   = (u16*)bf_rgn;                  // 1,048,576 u16 (=524,288 f)
  u16*   yb    = (u16*)(bf_rgn + 524288);       // 2,097,152 u16
  u16*   WinB  = (u16*)(bf_rgn + 524288 + 1048576);            // 4,194,304 u16
  u16*   WoutB = (u16*)(bf_rgn + 524288 + 1048576 + 2097152);  // 2,097,152 u16
  // total: 17,825,792 floats = 71.3 MB
  float* xln     = y;                   // prologue-only, overlays y
  float* partial = xz;                  // epilogue-only, overlays xz
  float* t1      = xz + 16384;

  prep_kernel<<<16384, 256, 0, stream>>>(W_dt, W_x, W_in, W_out, wdtT, wxT, WinB, WoutB);
  ln7_kernel<<<(B_*SEQ_+255)/256, 256, 0, stream>>>(x, in_g, in_b, xln);
  embed_kernel<<<TOK_, 256, 0, stream>>>(xln, pe_W, pe_b, h);

  for (int l = 0; l < NL_; l++){
    ln512_kernel<<<TOK_, 256, 0, stream>>>(h, ln_g + l*DM_, ln_b + l*DM_, un, unb);
    gemm_bf16<128,128,false><<<dim3(2*DI_/128, TOK_/128), 256, 0, stream>>>(
        unb, WinB + (size_t)l*2*DI_*DM_, xz, DM_, DM_, DM_, 2*DI_);
    conv_silu_kernel<<<(TOK_*DI_)/256, 256, 0, stream>>>(
        xz, conv_W + (size_t)l*DI_*DC_, conv_b + (size_t)l*DI_, xc);
    dbl_kernel<<<TOK_/4, 256, 0, stream>>>(xc, wxT + (size_t)l*DI_*64, dblb);
    delta_kernel<<<dim3(DI_/256, TOK_), 256, 0, stream>>>(
        dblb, wdtT + (size_t)l*DTR_*DI_, b_dt + (size_t)l*DI_, delta);
    scan_kernel<<<dim3(DI_/16, B_), 256, 0, stream>>>(
        delta, xc, dblb, A_log + (size_t)l*DI_*NS_, y);
    ymix_kernel<<<(TOK_*DI_)/256, 256, 0, stream>>>(y, xc, xz, Dskip + (size_t)l*DI_, yb);
    gemm_bf16<64,64,true><<<dim3(DM_/64, TOK_/64), 256, 0, stream>>>(
        yb, WoutB + (size_t)l*DM_*DI_, h, DI_, DI_, DI_, DM_);
  }

  ln512_kernel<<<TOK_, 256, 0, stream>>>(h, fn_g, fn_b, un, unb);
  head1_kernel<<<dim3(128, 16), 256, 0, stream>>>(un, hW1, partial);
  head_combine_kernel<<<4, 256, 0, stream>>>(partial, hb1, t1);
  head2_kernel<<<6, 128, 0, stream>>>(t1, hW2, hb2, (float*)d_out);
}